// Round 12
// baseline (994.393 us; speedup 1.0000x reference)
//
#include <hip/hip_runtime.h>

typedef long long ll;
typedef __attribute__((ext_vector_type(8))) short short8;
typedef __attribute__((ext_vector_type(4))) float f32x4;
constexpr int HID = 256;
constexpr int LDSS = 264;   // LDS row stride in shorts: 528B, 16B-aligned, ~2-way banks (free)

__device__ inline ushort f2bf(float f){
  uint u = __float_as_uint(f);
  u += 0x7FFFu + ((u >> 16) & 1u);
  return (ushort)(u >> 16);
}

// feature permutation: pos q = pi(c) groups the MFMA C-fragment's 4 nf-values contiguously.
// pi(c) = (c&~63) | ((c&15)*4 + ((c>>4)&3));  pinv is its inverse.
__device__ inline int pinv(int q){ return (q & ~63) | ((q & 3)*16 + ((q >> 2) & 15)); }

__device__ inline void bfacc(uint2 u, float4& a){
  a.x += __uint_as_float(u.x << 16);
  a.y += __uint_as_float(u.x & 0xFFFF0000u);
  a.z += __uint_as_float(u.y << 16);
  a.w += __uint_as_float(u.y & 0xFFFF0000u);
}

// ---------------- diagnostics ----------------
__global__ void k_diag(float* out, int n, float val){
  int i = blockIdx.x*256 + threadIdx.x;
  if (i < n) out[i] = val;
}

// flag=1 if edge_index is int64 (all high words of first 2048 entries zero)
__global__ void k_detect(const int* ei, int* flag){
  __shared__ int bad;
  if (threadIdx.x == 0) bad = 0;
  __syncthreads();
  for (int i = threadIdx.x; i < 2048; i += 256)
    if (ei[2*i+1] != 0) bad = 1;
  __syncthreads();
  if (threadIdx.x == 0) *flag = bad ? 0 : 1;
}

// ---------------- graph preprocessing ----------------
__global__ void k_count(const int* ei, ll E, const int* flag, int* cnt){
  ll i = (ll)blockIdx.x*256 + threadIdx.x;
  if (i >= E) return;
  int f = *flag;
  int d = f ? (int)((const ll*)ei)[E + i] : ei[E + i];
  atomicAdd(&cnt[d], 1);
}

// ---- multi-block scan ----
__global__ void k_scan_a(const int* __restrict__ cnt, int* __restrict__ bsum, int n){
  __shared__ int s[256];
  int t = threadIdx.x, i = blockIdx.x*256 + t;
  s[t] = (i < n) ? cnt[i] : 0;
  __syncthreads();
  for (int off = 128; off; off >>= 1){
    if (t < off) s[t] += s[t + off];
    __syncthreads();
  }
  if (t == 0) bsum[blockIdx.x] = s[0];
}

__global__ void k_scan_b(const int* __restrict__ bsum, int* __restrict__ boff,
                         int nb, int* __restrict__ row_ptr, int n){
  __shared__ int s[256];
  int t = threadIdx.x;
  int v = (t < nb) ? bsum[t] : 0;
  s[t] = v; __syncthreads();
  for (int off = 1; off < 256; off <<= 1){
    int add = (t >= off) ? s[t - off] : 0;
    __syncthreads();
    s[t] += add;
    __syncthreads();
  }
  if (t < nb) boff[t] = s[t] - v;
  if (t == nb - 1) row_ptr[n] = s[t];
}

// scan_c + dinv/xd fused
__global__ void k_scan_c(const int* __restrict__ cnt, const int* __restrict__ boff,
                         int* __restrict__ row_ptr, const float* __restrict__ x,
                         float* __restrict__ dinv, float* __restrict__ xd, int n){
  __shared__ int s[256];
  int t = threadIdx.x, i = blockIdx.x*256 + t;
  int v = (i < n) ? cnt[i] : 0;
  s[t] = v; __syncthreads();
  for (int off = 1; off < 256; off <<= 1){
    int add = (t >= off) ? s[t - off] : 0;
    __syncthreads();
    s[t] += add;
    __syncthreads();
  }
  if (i < n){
    row_ptr[i] = boff[blockIdx.x] + s[t] - v;
    float dv = 1.0f / sqrtf((float)(v + 1));
    dinv[i] = dv;
    xd[i] = x[i] * dv;
  }
}

__global__ void k_place(const int* ei, ll E, const int* flag, int* fill, int* col){
  ll i = (ll)blockIdx.x*256 + threadIdx.x;
  if (i >= E) return;
  int f = *flag;
  int s, d;
  if (f){ const ll* e64 = (const ll*)ei; s = (int)e64[i]; d = (int)e64[E + i]; }
  else  { s = ei[i]; d = ei[E + i]; }
  int p = atomicAdd(&fill[d], 1);
  col[p] = s;
}

// conv1 is rank-1: g[d] = xd[d] + sum_{s->d} xd[s]   (so Ah1 = dinv*g is conv1's input row scale)
__global__ void k_layer1(const float* __restrict__ xd, const int* __restrict__ row_ptr,
                         const int* __restrict__ col, float* __restrict__ g, int n){
  int i = blockIdx.x*256 + threadIdx.x;
  if (i >= n) return;
  float s = xd[i];
  int e0 = row_ptr[i], e1 = row_ptr[i+1];
  for (int e = e0; e < e1; ++e) s += xd[col[e]];
  g[i] = s;
}

// ---------------- permuted parameter tables (one block) ----------------
__global__ void k_perm(const float* b1, const float* W1, const float* bm, const float* Wc,
                       float* b1_p, float* W1_p, float* bm_p, float* Wc_p){
  int q = threadIdx.x;
  int c = pinv(q);
  b1_p[q] = b1[c];
  W1_p[q] = W1[c];
  bm_p[q] = bm[c];
  Wc_p[q] = Wc[c];
}

// ---------------- W split: fp32 -> (hi,lo) bf16, MFMA-fragment-major, K permuted ----------------
__global__ void k_splitW(const float* __restrict__ W, short* __restrict__ Bt){
  int idx = blockIdx.x*256 + threadIdx.x;
  if (idx >= 16*8*64) return;
  int nb = idx >> 9, kc = (idx >> 6) & 7, l = idx & 63;
  short8 hi, lo;
  #pragma unroll
  for (int j = 0; j < 8; ++j){
    int k = pinv(kc*32 + ((l >> 4) * 8) + j);
    int c = nb*16 + (l & 15);
    float wv = W[k*HID + c];
    ushort h = f2bf(wv);
    float hf = __uint_as_float((uint)h << 16);
    hi[j] = (short)h;
    lo[j] = (short)f2bf(wv - hf);
  }
  ((short8*)Bt)[idx] = hi;
  ((short8*)Bt)[8192 + idx] = lo;
}

// ---------------- conv1 expand (rank-1, elementwise): Hs1 = bf16(dinv * relu(dinv*g*W1 + b1)) ----
__global__ __launch_bounds__(256) void k_expand1(
  const float* __restrict__ g, const float* __restrict__ dinv,
  const float* __restrict__ W1_p, const float* __restrict__ b1_p,
  ushort* __restrict__ Hs, int n)
{
  int v = (int)((blockIdx.x*256 + threadIdx.x) >> 6);
  int lane = threadIdx.x & 63;
  if (v >= n) return;
  float dv = dinv[v];
  float gv = dv * g[v];
  float4 w1 = ((const float4*)W1_p)[lane];
  float4 bb = ((const float4*)b1_p)[lane];
  uint2 o;
  o.x = (uint)f2bf(dv * fmaxf(fmaf(gv, w1.x, bb.x), 0.f))
      | ((uint)f2bf(dv * fmaxf(fmaf(gv, w1.y, bb.y), 0.f)) << 16);
  o.y = (uint)f2bf(dv * fmaxf(fmaf(gv, w1.z, bb.z), 0.f))
      | ((uint)f2bf(dv * fmaxf(fmaf(gv, w1.w, bb.w), 0.f)) << 16);
  ((uint2*)Hs)[(size_t)v*64 + lane] = o;
}

// ---------------- FUSED layer: gather(Hs) -> LDS A-tile -> MFMA*W -> Hs_out ----------------
// Uses (A H) W = A (H W): gather neighbor-sums of the pre-scaled state Hs = dinv.h (bf16,
// pi-ordered), stage A = bf16(dinv_dst * Z) in LDS, then one MFMA pass with hi/lo W.
// LAST=0: Hs_out = bf16(dinv * relu(acc + b));  LAST=1: Hs_out = bf16(relu(acc + b)) (= h10).
// Block = 64 dst nodes; wave w gathers nodes [w*16, w*16+16) sequentially, 64 lanes x 8B/row.
template<int LAST>
__global__ __launch_bounds__(256, 4) void k_fused(
  const ushort* __restrict__ Hs, const int* __restrict__ row_ptr,
  const int* __restrict__ col, const short* __restrict__ Bt,
  const float* __restrict__ bias_p, const float* __restrict__ dinv,
  ushort* __restrict__ Hs_out, int n)
{
  __shared__ short Ah[64*LDSS];   // 33.8 KB
  int t = threadIdx.x;
  int lane = t & 63, w = t >> 6;
  int r0 = blockIdx.x * 64;

  // ---- phase 1: gather 16 rows per wave, 8-deep MLP, fp32 accum ----
  const uint2* hsp = ((const uint2*)Hs) + lane;   // row c at + c*64
  for (int i = 0; i < 16; ++i){
    int row = w*16 + i;
    int v = r0 + row;
    uint2 o = make_uint2(0u, 0u);
    if (v < n){
      float4 a0 = make_float4(0.f,0.f,0.f,0.f);
      float4 a1 = make_float4(0.f,0.f,0.f,0.f);
      float4 a2 = make_float4(0.f,0.f,0.f,0.f);
      float4 a3 = make_float4(0.f,0.f,0.f,0.f);
      bfacc(hsp[(size_t)v*64], a0);               // self-loop
      int e0 = row_ptr[v], e1 = row_ptr[v+1];
      int e = e0;
      for (; e + 8 <= e1; e += 8){
        int c[8];
        #pragma unroll
        for (int j = 0; j < 8; ++j) c[j] = __builtin_nontemporal_load(col + e + j);
        uint2 vv[8];
        #pragma unroll
        for (int j = 0; j < 8; ++j) vv[j] = hsp[(size_t)c[j]*64];
        bfacc(vv[0], a0); bfacc(vv[1], a1); bfacc(vv[2], a2); bfacc(vv[3], a3);
        bfacc(vv[4], a0); bfacc(vv[5], a1); bfacc(vv[6], a2); bfacc(vv[7], a3);
      }
      for (; e + 2 <= e1; e += 2){
        int c0 = __builtin_nontemporal_load(col + e);
        int c1 = __builtin_nontemporal_load(col + e + 1);
        uint2 v0 = hsp[(size_t)c0*64];
        uint2 v1 = hsp[(size_t)c1*64];
        bfacc(v0, a0); bfacc(v1, a1);
      }
      if (e < e1){
        uint2 vv = hsp[(size_t)__builtin_nontemporal_load(col + e)*64];
        bfacc(vv, a0);
      }
      a0.x += a1.x + a2.x + a3.x;
      a0.y += a1.y + a2.y + a3.y;
      a0.z += a1.z + a2.z + a3.z;
      a0.w += a1.w + a2.w + a3.w;
      float dv = dinv[v];                         // A-row = dinv_dst * Z (bias/relu post-GEMM)
      o.x = (uint)f2bf(dv * a0.x) | ((uint)f2bf(dv * a0.y) << 16);
      o.y = (uint)f2bf(dv * a0.z) | ((uint)f2bf(dv * a0.w) << 16);
    }
    *(uint2*)&Ah[row*LDSS + lane*4] = o;          // pi-ordered row in LDS
  }
  __syncthreads();

  // ---- phase 2: MFMA, wave w covers cols [w*64, w*64+64) ----
  const short8* Btv = (const short8*)Bt;
  f32x4 acc[4][4];
  #pragma unroll
  for (int m = 0; m < 4; ++m)
    #pragma unroll
    for (int nf = 0; nf < 4; ++nf)
      acc[m][nf] = (f32x4){0.f,0.f,0.f,0.f};

  for (int kc = 0; kc < 8; ++kc){
    short8 ah[4];
    #pragma unroll
    for (int m = 0; m < 4; ++m){
      int row = m*16 + (lane & 15);
      ah[m] = *(const short8*)&Ah[row*LDSS + (kc*4 + (lane >> 4))*8];
    }
    #pragma unroll
    for (int nf = 0; nf < 4; ++nf){
      int nb = w*4 + nf;
      short8 bh = Btv[(size_t)(nb*8 + kc)*64 + lane];
      short8 bl = Btv[(size_t)8192 + (nb*8 + kc)*64 + lane];
      #pragma unroll
      for (int m = 0; m < 4; ++m){
        acc[m][nf] = __builtin_amdgcn_mfma_f32_16x16x32_bf16(ah[m], bh, acc[m][nf], 0,0,0);
        acc[m][nf] = __builtin_amdgcn_mfma_f32_16x16x32_bf16(ah[m], bl, acc[m][nf], 0,0,0);
      }
    }
  }

  // ---- epilogue: Hs_out = bf16(scale * relu(acc + b)), pi-ordered 8B stores ----
  float4 bb = *(const float4*)(bias_p + w*64 + (lane & 15)*4);
  #pragma unroll
  for (int m = 0; m < 4; ++m){
    #pragma unroll
    for (int r = 0; r < 4; ++r){
      int v = r0 + m*16 + ((lane >> 4)*4) + r;
      if (v < n){
        float sc = LAST ? 1.0f : dinv[v];
        uint2 o;
        o.x = (uint)f2bf(sc * fmaxf(acc[m][0][r] + bb.x, 0.f))
            | ((uint)f2bf(sc * fmaxf(acc[m][1][r] + bb.y, 0.f)) << 16);
        o.y = (uint)f2bf(sc * fmaxf(acc[m][2][r] + bb.z, 0.f))
            | ((uint)f2bf(sc * fmaxf(acc[m][3][r] + bb.w, 0.f)) << 16);
        *(uint2*)((char*)Hs_out + (size_t)v*512 + w*128 + (lane & 15)*8) = o;
      }
    }
  }
}

// ---------------- final: out[v] = h10[v] . Wc + bc  (h10 pi-ordered bf16) ----------------
__global__ __launch_bounds__(256) void k_out(
  const ushort* __restrict__ H, const float* __restrict__ Wc_p,
  const float* __restrict__ bc, float* __restrict__ out, int n)
{
  int v = (int)((blockIdx.x*256 + threadIdx.x) >> 6);
  int lane = threadIdx.x & 63;
  if (v >= n) return;
  uint2 u = ((const uint2*)H)[(size_t)v*64 + lane];
  float4 wc = ((const float4*)Wc_p)[lane];
  float s = __uint_as_float(u.x << 16)          * wc.x
          + __uint_as_float(u.x & 0xFFFF0000u)  * wc.y
          + __uint_as_float(u.y << 16)          * wc.z
          + __uint_as_float(u.y & 0xFFFF0000u)  * wc.w;
  #pragma unroll
  for (int off = 32; off; off >>= 1) s += __shfl_down(s, off, 64);
  if (lane == 0) out[v] = s + bc[0];
}

// ---------------- launch ----------------
extern "C" void kernel_launch(void* const* d_in, const int* in_sizes, int n_in,
                              void* d_out, int out_size, void* d_ws, size_t ws_size,
                              hipStream_t stream)
{
  const float* x  = (const float*)d_in[0];
  const int*   ei = (const int*)d_in[1];
  const float* W1 = (const float*)d_in[2];
  const float* b1 = (const float*)d_in[3];
  const float* Wm = (const float*)d_in[4];
  const float* bm = (const float*)d_in[5];
  const float* Wc = (const float*)d_in[6];
  const float* bc = (const float*)d_in[7];
  float* out = (float*)d_out;
  const int N = in_sizes[0];
  const ll  E = in_sizes[1] / 2;

  char* ws = (char*)d_ws;
  size_t off = 0;
  auto carve = [&](size_t bytes)->char*{
    char* p = ws + off; off += (bytes + 255) & ~(size_t)255; return p;
  };
  int*   cnt     = (int*)  carve((size_t)N*4);
  int*   row_ptr = (int*)  carve((size_t)(N+1)*4);
  int*   fill    = (int*)  carve((size_t)N*4);
  float* dinv    = (float*)carve((size_t)N*4);
  float* xd      = (float*)carve((size_t)N*4);
  float* g       = (float*)carve((size_t)N*4);
  int*   flag    = (int*)  carve(256);
  int*   bsum    = (int*)  carve(1024);
  int*   boff    = (int*)  carve(1024);
  float* b1_p    = (float*)carve(1024);
  float* W1_p    = (float*)carve(1024);
  float* bm_p    = (float*)carve(1024);
  float* Wc_p    = (float*)carve(1024);
  short* Bt      = (short*)carve((size_t)2*8192*8*2);   // 256 KB
  int*   col     = (int*)  carve((size_t)E*4);
  ushort* Hs_a   = (ushort*)carve((size_t)N*HID*2);     // 25.6 MB, pi-ordered, dinv-prescaled
  ushort* Hs_b   = (ushort*)carve((size_t)N*HID*2);     // 25.6 MB
  if (off > ws_size){
    k_diag<<<(out_size+255)/256, 256, 0, stream>>>(out, out_size, (float)(ws_size >> 20));
    return;
  }

  hipMemsetAsync(cnt, 0, (size_t)N*4, stream);
  k_detect<<<1, 256, 0, stream>>>(ei, flag);
  int eblocks = (int)((E + 255) / 256);
  k_count<<<eblocks, 256, 0, stream>>>(ei, E, flag, cnt);
  int nb = (N + 255) / 256;
  k_scan_a<<<nb, 256, 0, stream>>>(cnt, bsum, N);
  k_scan_b<<<1, 256, 0, stream>>>(bsum, boff, nb, row_ptr, N);
  k_scan_c<<<nb, 256, 0, stream>>>(cnt, boff, row_ptr, x, dinv, xd, N);
  hipMemcpyAsync(fill, row_ptr, (size_t)N*4, hipMemcpyDeviceToDevice, stream);
  k_place<<<eblocks, 256, 0, stream>>>(ei, E, flag, fill, col);
  k_perm<<<1, 256, 0, stream>>>(b1, W1, bm, Wc, b1_p, W1_p, bm_p, Wc_p);
  k_splitW<<<32, 256, 0, stream>>>(Wm, Bt);
  k_layer1<<<(N+255)/256, 256, 0, stream>>>(xd, row_ptr, col, g, N);

  int vblocks = (N + 3) / 4;        // 1 wave per node
  int fblocks = (N + 63) / 64;      // 64 nodes per fused block
  // conv1: rank-1 elementwise expand -> Hs1
  k_expand1<<<vblocks, 256, 0, stream>>>(g, dinv, W1_p, b1_p, Hs_a, N);
  // conv2..conv9: fused gather+GEMM (state stays dinv-prescaled)
  ushort* cur = Hs_a; ushort* nxt = Hs_b;
  for (int l = 0; l < 8; ++l){
    k_fused<0><<<fblocks, 256, 0, stream>>>(cur, row_ptr, col, Bt, bm_p, dinv, nxt, N);
    ushort* tmp = cur; cur = nxt; nxt = tmp;
  }
  // conv10: fused, writes unscaled h10
  k_fused<1><<<fblocks, 256, 0, stream>>>(cur, row_ptr, col, Bt, bm_p, dinv, nxt, N);
  // readout
  k_out<<<vblocks, 256, 0, stream>>>(nxt, Wc_p, bc, out, N);
}

// Round 13
// 845.009 us; speedup vs baseline: 1.1768x; 1.1768x over previous
//
#include <hip/hip_runtime.h>

typedef long long ll;
typedef __attribute__((ext_vector_type(8))) short short8;
typedef __attribute__((ext_vector_type(4))) float f32x4;
constexpr int HID = 256;
constexpr int LDSS = 264;   // LDS row stride in shorts: 528B, 16B-aligned, ~2-way banks (free)

__device__ inline ushort f2bf(float f){
  uint u = __float_as_uint(f);
  u += 0x7FFFu + ((u >> 16) & 1u);
  return (ushort)(u >> 16);
}

// feature permutation: pos q = pi(c) groups the MFMA C-fragment's 4 nf-values contiguously.
// pi(c) = (c&~63) | ((c&15)*4 + ((c>>4)&3));  pinv is its inverse.
__device__ inline int pinv(int q){ return (q & ~63) | ((q & 3)*16 + ((q >> 2) & 15)); }

// ---------------- diagnostics ----------------
__global__ void k_diag(float* out, int n, float val){
  int i = blockIdx.x*256 + threadIdx.x;
  if (i < n) out[i] = val;
}

// flag=1 if edge_index is int64 (all high words of first 2048 entries zero)
__global__ void k_detect(const int* ei, int* flag){
  __shared__ int bad;
  if (threadIdx.x == 0) bad = 0;
  __syncthreads();
  for (int i = threadIdx.x; i < 2048; i += 256)
    if (ei[2*i+1] != 0) bad = 1;
  __syncthreads();
  if (threadIdx.x == 0) *flag = bad ? 0 : 1;
}

// ---------------- graph preprocessing ----------------
__global__ void k_count(const int* ei, ll E, const int* flag, int* cnt){
  ll i = (ll)blockIdx.x*256 + threadIdx.x;
  if (i >= E) return;
  int f = *flag;
  int d = f ? (int)((const ll*)ei)[E + i] : ei[E + i];
  atomicAdd(&cnt[d], 1);
}

// ---- multi-block scan ----
__global__ void k_scan_a(const int* __restrict__ cnt, int* __restrict__ bsum, int n){
  __shared__ int s[256];
  int t = threadIdx.x, i = blockIdx.x*256 + t;
  s[t] = (i < n) ? cnt[i] : 0;
  __syncthreads();
  for (int off = 128; off; off >>= 1){
    if (t < off) s[t] += s[t + off];
    __syncthreads();
  }
  if (t == 0) bsum[blockIdx.x] = s[0];
}

__global__ void k_scan_b(const int* __restrict__ bsum, int* __restrict__ boff,
                         int nb, int* __restrict__ row_ptr, int n){
  __shared__ int s[256];
  int t = threadIdx.x;
  int v = (t < nb) ? bsum[t] : 0;
  s[t] = v; __syncthreads();
  for (int off = 1; off < 256; off <<= 1){
    int add = (t >= off) ? s[t - off] : 0;
    __syncthreads();
    s[t] += add;
    __syncthreads();
  }
  if (t < nb) boff[t] = s[t] - v;
  if (t == nb - 1) row_ptr[n] = s[t];
}

// scan_c + dinv/xd fused
__global__ void k_scan_c(const int* __restrict__ cnt, const int* __restrict__ boff,
                         int* __restrict__ row_ptr, const float* __restrict__ x,
                         float* __restrict__ dinv, float* __restrict__ xd, int n){
  __shared__ int s[256];
  int t = threadIdx.x, i = blockIdx.x*256 + t;
  int v = (i < n) ? cnt[i] : 0;
  s[t] = v; __syncthreads();
  for (int off = 1; off < 256; off <<= 1){
    int add = (t >= off) ? s[t - off] : 0;
    __syncthreads();
    s[t] += add;
    __syncthreads();
  }
  if (i < n){
    row_ptr[i] = boff[blockIdx.x] + s[t] - v;
    float dv = 1.0f / sqrtf((float)(v + 1));
    dinv[i] = dv;
    xd[i] = x[i] * dv;
  }
}

__global__ void k_place(const int* ei, ll E, const int* flag, int* fill, int* col){
  ll i = (ll)blockIdx.x*256 + threadIdx.x;
  if (i >= E) return;
  int f = *flag;
  int s, d;
  if (f){ const ll* e64 = (const ll*)ei; s = (int)e64[i]; d = (int)e64[E + i]; }
  else  { s = ei[i]; d = ei[E + i]; }
  int p = atomicAdd(&fill[d], 1);
  col[p] = s;
}

// layer 1 is rank-1: g[d] = xd[d] + sum_{s->d} xd[s]
__global__ void k_layer1(const float* __restrict__ xd, const int* __restrict__ row_ptr,
                         const int* __restrict__ col, float* __restrict__ g, int n){
  int i = blockIdx.x*256 + threadIdx.x;
  if (i >= n) return;
  float s = xd[i];
  int e0 = row_ptr[i], e1 = row_ptr[i+1];
  for (int e = e0; e < e1; ++e) s += xd[col[e]];
  g[i] = s;
}

// ---------------- prep: W -> single bf16, MFMA-fragment-major, K permuted; + permuted params ----
// Blocks 0..31: Bt slot (nb,kc,l,j) = bf16(W[pinv(kc*32+(l>>4)*8+j)][nb*16+(l&15)]).
// Block 32: permuted parameter tables.
__global__ void k_prep(const float* __restrict__ W, short* __restrict__ Bt,
                       const float* b1, const float* W1, const float* bm, const float* Wc,
                       float* b1_p, float* W1_p, float* bm_p, float* Wc_p){
  int idx = blockIdx.x*256 + threadIdx.x;
  if (idx < 16*8*64){
    int nb = idx >> 9, kc = (idx >> 6) & 7, l = idx & 63;
    short8 hi;
    #pragma unroll
    for (int j = 0; j < 8; ++j){
      int k = pinv(kc*32 + ((l >> 4) * 8) + j);
      int c = nb*16 + (l & 15);
      hi[j] = (short)f2bf(W[k*HID + c]);
    }
    ((short8*)Bt)[idx] = hi;
  } else if (blockIdx.x == 32){
    int q = threadIdx.x;
    int c = pinv(q);
    b1_p[q] = b1[c];
    W1_p[q] = W1[c];
    bm_p[q] = bm[c];
    Wc_p[q] = Wc[c];
  }
}

// ---------------- MFMA GEMM: ts_bf = bf16( (A @ W) * dinv_row ), pi-ordered rows ----------------
// MODE 0: A[v][q] = bf16(relu(dinv[v]*g[v]*W1_p[q] + b1_p[q]))  (positions q, permuted params)
// MODE 1: A = Abf (bf16, pi-ordered, transform already applied by scatter epilogue)
// Single-bf16 W (A is bf16 anyway; rounding noise averages over K=256).
template<int MODE>
__global__ __launch_bounds__(256, 4) void k_gemm_mfma(
  const void* __restrict__ Ain, const short* __restrict__ Bt,
  const float* __restrict__ bias, const float* __restrict__ W1,
  const float* __restrict__ dinv, ushort* __restrict__ ts_bf, int n)
{
  __shared__ short Ah[64*LDSS];   // 33.8 KB
  int t = threadIdx.x;
  int r0 = blockIdx.x * 64;

  // ---- stage A tile: 64 rows x 256 bf16 (pi-ordered positions) ----
  #pragma unroll
  for (int i = 0; i < 8; ++i){
    int id  = i*256 + t;           // 16B-chunk id, 0..2047
    int row = id >> 5;             // 0..63
    int c16 = id & 31;             // 16B chunk (8 positions) within row
    int v   = r0 + row;
    short8 hi8 = {0,0,0,0,0,0,0,0};
    if (v < n){
      if (MODE == 0){
        float gv = dinv[v] * ((const float*)Ain)[v];
        const float4* wp = (const float4*)(W1 + c16*8);
        const float4* bp = (const float4*)(bias + c16*8);
        float4 w0 = wp[0], w1 = wp[1], b0 = bp[0], b1 = bp[1];
        hi8[0] = (short)f2bf(fmaxf(fmaf(gv,w0.x,b0.x), 0.f));
        hi8[1] = (short)f2bf(fmaxf(fmaf(gv,w0.y,b0.y), 0.f));
        hi8[2] = (short)f2bf(fmaxf(fmaf(gv,w0.z,b0.z), 0.f));
        hi8[3] = (short)f2bf(fmaxf(fmaf(gv,w0.w,b0.w), 0.f));
        hi8[4] = (short)f2bf(fmaxf(fmaf(gv,w1.x,b1.x), 0.f));
        hi8[5] = (short)f2bf(fmaxf(fmaf(gv,w1.y,b1.y), 0.f));
        hi8[6] = (short)f2bf(fmaxf(fmaf(gv,w1.z,b1.z), 0.f));
        hi8[7] = (short)f2bf(fmaxf(fmaf(gv,w1.w,b1.w), 0.f));
      } else {
        hi8 = ((const short8*)Ain)[(size_t)v*32 + c16];
      }
    }
    *(short8*)&Ah[row*LDSS + c16*8] = hi8;
  }
  __syncthreads();

  // ---- MFMA: wave w covers cols [w*64, w*64+64) ----
  int l = t & 63, w = t >> 6;
  const short8* Btv = (const short8*)Bt;
  f32x4 acc[4][4];
  #pragma unroll
  for (int m = 0; m < 4; ++m)
    #pragma unroll
    for (int nf = 0; nf < 4; ++nf)
      acc[m][nf] = (f32x4){0.f,0.f,0.f,0.f};

  for (int kc = 0; kc < 8; ++kc){
    short8 ah[4];
    #pragma unroll
    for (int m = 0; m < 4; ++m){
      int row = m*16 + (l & 15);
      ah[m] = *(const short8*)&Ah[row*LDSS + (kc*4 + (l >> 4))*8];
    }
    #pragma unroll
    for (int nf = 0; nf < 4; ++nf){
      int nb = w*4 + nf;
      short8 bh = Btv[(size_t)(nb*8 + kc)*64 + l];
      #pragma unroll
      for (int m = 0; m < 4; ++m){
        acc[m][nf] = __builtin_amdgcn_mfma_f32_16x16x32_bf16(ah[m], bh, acc[m][nf], 0,0,0);
      }
    }
  }

  // ---- store ts_bf pi-ordered, pre-scaled by dinv[src]: one 8B store per (m,r) ----
  #pragma unroll
  for (int m = 0; m < 4; ++m){
    #pragma unroll
    for (int r = 0; r < 4; ++r){
      int v = r0 + m*16 + ((l >> 4)*4) + r;
      if (v < n){
        float dv = dinv[v];
        uint2 o;
        o.x = (uint)f2bf(dv * acc[m][0][r]) | ((uint)f2bf(dv * acc[m][1][r]) << 16);
        o.y = (uint)f2bf(dv * acc[m][2][r]) | ((uint)f2bf(dv * acc[m][3][r]) << 16);
        *(uint2*)((char*)ts_bf + (size_t)v*512 + w*128 + (l & 15)*8) = o;
      }
    }
  }
}

// ---------------- propagate + fused transform (node-major, 4-deep; round-6 best shape) ----------
__device__ inline void bfacc(uint2 u, float4& a){
  a.x += __uint_as_float(u.x << 16);
  a.y += __uint_as_float(u.x & 0xFFFF0000u);
  a.z += __uint_as_float(u.y << 16);
  a.w += __uint_as_float(u.y & 0xFFFF0000u);
}

template<int LAST>
__global__ __launch_bounds__(256, 4) void k_scatter_bf(
  const ushort* __restrict__ ts_bf, const int* __restrict__ row_ptr,
  const int* __restrict__ col, const float* __restrict__ bias,
  const float* __restrict__ dinv, ushort* __restrict__ Abf,
  const float* __restrict__ Wc, const float* __restrict__ bc,
  float* __restrict__ out, int n)
{
  int w = (int)((blockIdx.x*256 + threadIdx.x) >> 6);
  int lane = threadIdx.x & 63;
  if (w >= n) return;
  const uint2* tsp = ((const uint2*)ts_bf) + lane;   // row c at + c*64
  int e0 = row_ptr[w], e1 = row_ptr[w+1];

  float4 a0 = make_float4(0.f,0.f,0.f,0.f);
  float4 a1 = make_float4(0.f,0.f,0.f,0.f);
  float4 a2 = make_float4(0.f,0.f,0.f,0.f);
  float4 a3 = make_float4(0.f,0.f,0.f,0.f);
  bfacc(tsp[(size_t)w*64], a0);                      // self-loop term

  int e = e0;
  for (; e + 4 <= e1; e += 4){
    int c0 = __builtin_nontemporal_load(col + e + 0);
    int c1 = __builtin_nontemporal_load(col + e + 1);
    int c2 = __builtin_nontemporal_load(col + e + 2);
    int c3 = __builtin_nontemporal_load(col + e + 3);
    uint2 v0 = tsp[(size_t)c0*64];
    uint2 v1 = tsp[(size_t)c1*64];
    uint2 v2 = tsp[(size_t)c2*64];
    uint2 v3 = tsp[(size_t)c3*64];
    bfacc(v0, a0); bfacc(v1, a1); bfacc(v2, a2); bfacc(v3, a3);
  }
  for (; e < e1; ++e){
    uint2 v = tsp[(size_t)__builtin_nontemporal_load(col + e)*64];
    bfacc(v, a0);
  }

  a0.x += a1.x + a2.x + a3.x;
  a0.y += a1.y + a2.y + a3.y;
  a0.z += a1.z + a2.z + a3.z;
  a0.w += a1.w + a2.w + a3.w;

  float dv = dinv[w];
  float4 bb = ((const float4*)bias)[lane];
  if (LAST == 0){
    uint2 o;
    o.x = (uint)f2bf(fmaxf(fmaf(dv, a0.x, bb.x), 0.f))
        | ((uint)f2bf(fmaxf(fmaf(dv, a0.y, bb.y), 0.f)) << 16);
    o.y = (uint)f2bf(fmaxf(fmaf(dv, a0.z, bb.z), 0.f))
        | ((uint)f2bf(fmaxf(fmaf(dv, a0.w, bb.w), 0.f)) << 16);
    ((uint2*)Abf)[(size_t)w*64 + lane] = o;
  } else {
    float4 wc = ((const float4*)Wc)[lane];
    float s = fmaxf(fmaf(dv, a0.x, bb.x), 0.f)*wc.x
            + fmaxf(fmaf(dv, a0.y, bb.y), 0.f)*wc.y
            + fmaxf(fmaf(dv, a0.z, bb.z), 0.f)*wc.z
            + fmaxf(fmaf(dv, a0.w, bb.w), 0.f)*wc.w;
    #pragma unroll
    for (int off = 32; off; off >>= 1) s += __shfl_down(s, off, 64);
    if (lane == 0) out[w] = s + bc[0];
  }
}

// ---------------- launch ----------------
extern "C" void kernel_launch(void* const* d_in, const int* in_sizes, int n_in,
                              void* d_out, int out_size, void* d_ws, size_t ws_size,
                              hipStream_t stream)
{
  const float* x  = (const float*)d_in[0];
  const int*   ei = (const int*)d_in[1];
  const float* W1 = (const float*)d_in[2];
  const float* b1 = (const float*)d_in[3];
  const float* Wm = (const float*)d_in[4];
  const float* bm = (const float*)d_in[5];
  const float* Wc = (const float*)d_in[6];
  const float* bc = (const float*)d_in[7];
  float* out = (float*)d_out;
  const int N = in_sizes[0];
  const ll  E = in_sizes[1] / 2;

  char* ws = (char*)d_ws;
  size_t off = 0;
  auto carve = [&](size_t bytes)->char*{
    char* p = ws + off; off += (bytes + 255) & ~(size_t)255; return p;
  };
  int*   cnt     = (int*)  carve((size_t)N*4);
  int*   row_ptr = (int*)  carve((size_t)(N+1)*4);
  int*   fill    = (int*)  carve((size_t)N*4);
  float* dinv    = (float*)carve((size_t)N*4);
  float* xd      = (float*)carve((size_t)N*4);
  float* g       = (float*)carve((size_t)N*4);
  int*   flag    = (int*)  carve(256);
  int*   bsum    = (int*)  carve(1024);
  int*   boff    = (int*)  carve(1024);
  float* b1_p    = (float*)carve(1024);
  float* W1_p    = (float*)carve(1024);
  float* bm_p    = (float*)carve(1024);
  float* Wc_p    = (float*)carve(1024);
  short* Bt      = (short*)carve((size_t)8192*8*2);     // 128 KB, single bf16 W
  int*   col     = (int*)  carve((size_t)E*4);
  ushort* ts_bf  = (ushort*)carve((size_t)N*HID*2);     // 25.6 MB, pi-ordered
  ushort* Abf    = (ushort*)carve((size_t)N*HID*2);     // 25.6 MB, pi-ordered
  if (off > ws_size){
    k_diag<<<(out_size+255)/256, 256, 0, stream>>>(out, out_size, (float)(ws_size >> 20));
    return;
  }

  hipMemsetAsync(cnt, 0, (size_t)N*4, stream);
  k_detect<<<1, 256, 0, stream>>>(ei, flag);
  int eblocks = (int)((E + 255) / 256);
  k_count<<<eblocks, 256, 0, stream>>>(ei, E, flag, cnt);
  int nb = (N + 255) / 256;
  k_scan_a<<<nb, 256, 0, stream>>>(cnt, bsum, N);
  k_scan_b<<<1, 256, 0, stream>>>(bsum, boff, nb, row_ptr, N);
  k_scan_c<<<nb, 256, 0, stream>>>(cnt, boff, row_ptr, x, dinv, xd, N);
  hipMemcpyAsync(fill, row_ptr, (size_t)N*4, hipMemcpyDeviceToDevice, stream);
  k_place<<<eblocks, 256, 0, stream>>>(ei, E, flag, fill, col);
  k_prep<<<33, 256, 0, stream>>>(Wm, Bt, b1, W1, bm, Wc, b1_p, W1_p, bm_p, Wc_p);
  k_layer1<<<(N+255)/256, 256, 0, stream>>>(xd, row_ptr, col, g, N);

  int gblocks = (N + 63) / 64;
  int sblocks = (N + 3) / 4;
  // conv2 GEMM (A computed inline from rank-1 conv1 output), then propagate+transform
  k_gemm_mfma<0><<<gblocks, 256, 0, stream>>>(g, Bt, b1_p, W1_p, dinv, ts_bf, N);
  k_scatter_bf<0><<<sblocks, 256, 0, stream>>>(ts_bf, row_ptr, col, bm_p, dinv, Abf, Wc_p, bc, out, N);
  // conv3..conv9
  for (int l = 0; l < 7; ++l){
    k_gemm_mfma<1><<<gblocks, 256, 0, stream>>>(Abf, Bt, bm_p, nullptr, dinv, ts_bf, N);
    k_scatter_bf<0><<<sblocks, 256, 0, stream>>>(ts_bf, row_ptr, col, bm_p, dinv, Abf, Wc_p, bc, out, N);
  }
  // conv10 + fused readout
  k_gemm_mfma<1><<<gblocks, 256, 0, stream>>>(Abf, Bt, bm_p, nullptr, dinv, ts_bf, N);
  k_scatter_bf<1><<<sblocks, 256, 0, stream>>>(ts_bf, row_ptr, col, bm_p, dinv, Abf, Wc_p, bc, out, N);
}